// Round 10
// baseline (97.625 us; speedup 1.0000x reference)
//
#include <hip/hip_runtime.h>
#include <hip/hip_bf16.h>

// ---- problem constants (match reference) ----
#define HIN   721
#define WIN   1440
#define HOUT_ 361
#define WOUT_ 720
#define NB    4
#define CIN_  8
#define COUT_ 32
#define KT    9
#define NNZ_  32
// derived: PSCALE = 2, base_row(x) = 2x exactly, cols in [0,16)
// q = c*10 + 2s + e  (80 values), j = col>>1 (8 values)

typedef short  bsh8   __attribute__((ext_vector_type(8)));   // 8 bf16 (4 VGPR) MFMA frag
typedef float  f32x16 __attribute__((ext_vector_type(16)));  // 32x32 MFMA acc
typedef unsigned int u32x4 __attribute__((ext_vector_type(4)));

static __device__ __forceinline__ unsigned short f2bf(float f) {
  unsigned u = __builtin_bit_cast(unsigned, f);
  u += 0x7fffu + ((u >> 16) & 1u);      // RNE
  return (unsigned short)(u >> 16);
}

static __device__ __forceinline__ unsigned pack2(float a, float b) {
  __hip_bfloat162 h = __float22bfloat162_rn(make_float2(a, b));
  unsigned u; __builtin_memcpy(&u, &h, 4);
  return u;                              // a -> low 16, b -> high 16
}

// =====================================================================
// K1: build combined coefficients (unchanged — correct & fast).
//   C[x][o][q][j] = sum over taps (k,n) hitting (s,e,j) of w[o,c,k]*psi[k,x,n]
// =====================================================================
__global__ __launch_bounds__(256) void coeff_kernel(
    const int*   __restrict__ psi_idx,
    const float* __restrict__ psi_vals,
    const float* __restrict__ weight,
    unsigned short* __restrict__ Cg)
{
  __shared__ float Cl[256 * 81];           // 82944 B, stride 81 -> 2-way max
  __shared__ float wl[COUT_ * CIN_ * KT];  // 9216 B
  __shared__ float S[KT][80];              // 2880 B

  const int x = blockIdx.x, tid = threadIdx.x;

  for (int i = tid; i < KT * 80; i += 256) ((float*)S)[i] = 0.f;
  for (int i = tid; i < COUT_ * CIN_ * KT; i += 256) wl[i] = weight[i];
  __syncthreads();

  for (int i = tid; i < KT * NNZ_; i += 256) {   // scatter all 288 taps
    int k = i >> 5, n = i & 31;
    int gi  = (k * HOUT_ + x) * NNZ_ + n;
    int idx = psi_idx[gi];
    int r   = idx / WIN;
    int col = idx - r * WIN;               // in [0,16)
    int s   = r - 2 * x + 2;               // in [0,4] after reference clip
    int slot = (s * 2 + (col & 1)) * 8 + (col >> 1);
    atomicAdd(&S[k][slot], psi_vals[gi]);
  }
  __syncthreads();

  { // dense combine: thread owns (o = tid>>3, c = tid&7)
    const float* wrow = &wl[tid * KT];
    float w[KT];
    #pragma unroll
    for (int k = 0; k < KT; ++k) w[k] = wrow[k];
    float* seg = &Cl[tid * 81];
    #pragma unroll
    for (int slot = 0; slot < 80; ++slot) {
      float acc = 0.f;
      #pragma unroll
      for (int k = 0; k < KT; ++k) acc += w[k] * S[k][slot];
      seg[slot] = acc;
    }
  }
  __syncthreads();

  // writeback as 16B chunks: Cg[((x*8+j)*10+qb)*32+o][qi0..7]
  for (int chunk = tid; chunk < 8 * 10 * 32; chunk += 256) {
    int j   = chunk / 320;
    int rem = chunk - j * 320;
    int qb  = rem >> 5, o = rem & 31;
    u32x4 pack;
    #pragma unroll
    for (int h = 0; h < 4; ++h) {
      int q0 = qb * 8 + 2 * h;
      int c0 = q0 / 10, ql0 = q0 - c0 * 10;
      int q1 = q0 + 1;
      int c1 = q1 / 10, ql1 = q1 - c1 * 10;
      unsigned lo = f2bf(Cl[(o * CIN_ + c0) * 81 + ql0 * 8 + j]);
      unsigned hi = f2bf(Cl[(o * CIN_ + c1) * 81 + ql1 * 8 + j]);
      pack[h] = lo | (hi << 16);
    }
    *(u32x4*)&Cg[((size_t)x * 2560 + (size_t)((j * 10 + qb) * 32 + o)) * 8] = pack;
  }
}

// =====================================================================
// K2: main compute — WAVE-INDEPENDENT blocks (no __syncthreads at all).
// 1-wave (64-thread) workgroup owns a private 72-row x 176B LDS tile and
// a 32(o) x 64(p) output window. Rationale: in the R8 geometry wave wv
// only reads rows [wv*64, wv*64+70] -> the block barrier was pure convoy
// overhead keeping 3 co-resident blocks phase-locked. Free-running waves
// let the SIMD scheduler overlap wave A's staging with wave B's MFMAs.
//  - LDS 72*176 = 12672B -> 12 blocks/CU (152KB), 12 waves/CU.
//  - RST=176 (48 mod 128 walk) -> ds_read_b128 at the 8-dword/bank floor;
//    rowpair b128 writes <= 9/8 of floor (enumerated).
//  - intra-wave LDS RAW (write then read, same wave) needs only the
//    compiler-inserted lgkmcnt wait — no barrier.
//  - depth-2 A-frag prefetch; j=0/1 frags issued before staging.
// =====================================================================
#define WROWS 72
#define RST   176

__global__ __launch_bounds__(64, 3) void disco_main_kernel(
    const float* __restrict__ x,
    const unsigned short* __restrict__ Cg,
    float* __restrict__ out)
{
  __shared__ __align__(16) unsigned char Ut[WROWS * RST];  // 12672 B, wave-private

  // ---- bijective XCD-chunked decode: 17328 = 8 * 2166 ----
  const int g   = blockIdx.x;
  const int xcd = g & 7, lin = g >> 3;
  const int swz = xcd * 2166 + lin;
  const int xo  = swz / 48;
  const int rem = swz - xo * 48;
  const int b   = rem / 12;         // 0..3
  const int pw  = rem - b * 12;     // 0..11 (12 windows of 64 cols)
  const int po  = pw * 64;

  const int lane = threadIdx.x;     // 0..63, one wave
  const int half = lane >> 5;       // k-slice half (chunk parity)
  const int l31  = lane & 31;

  const unsigned short* cgx = Cg + (size_t)xo * 2560 * 8
                                 + (size_t)(half * 32 + l31) * 8;

  // ---- j=0 and j=1 A-frags issued first: in flight during staging ----
  bsh8 a0[5], a1[5];
  #pragma unroll
  for (int kb = 0; kb < 5; ++kb) a0[kb] = *(const bsh8*)&cgx[kb * 512];
  #pragma unroll
  for (int kb = 0; kb < 5; ++kb) a1[kb] = *(const bsh8*)&cgx[2560 + kb * 512];

  const float* xb = x + (size_t)b * (CIN_ * HIN * WIN);

  int rr[5];
  #pragma unroll
  for (int s = 0; s < 5; ++s) {
    int r = 2 * xo + s - 2;
    rr[s] = r < 0 ? 0 : (r > HIN - 1 ? HIN - 1 : r);
  }

  // ---- stage private tile: 360 units (ch = u/36, rp = u%36) ----
  // unit u: rows 2rp, 2rp+1 of chunk ch; 4 float4 loads (q-pairs 4ch+m)
  // batch 1: units k=0..2 (12 loads in flight), batch 2: k=3,4 + tail.
  {
    float4 v[3][4];
    #pragma unroll
    for (int k = 0; k < 3; ++k) {
      const int u  = lane + k * 64;
      const int ch = u / 36, rp = u - ch * 36;
      int cw = po + 2 * rp; if (cw >= WOUT_) cw -= WOUT_;
      #pragma unroll
      for (int m = 0; m < 4; ++m) {
        int qp = 4 * ch + m, c = (qp * 205) >> 10, s = qp - c * 5;
        v[k][m] = *(const float4*)&xb[(size_t)(c * HIN + rr[s]) * WIN + 2 * cw];
      }
    }
    #pragma unroll
    for (int k = 0; k < 3; ++k) {
      const int u  = lane + k * 64;
      const int ch = u / 36, rp = u - ch * 36;
      u32x4 lo, hi;
      #pragma unroll
      for (int m = 0; m < 4; ++m) { lo[m] = pack2(v[k][m].x, v[k][m].y);
                                    hi[m] = pack2(v[k][m].z, v[k][m].w); }
      const int byte0 = (2 * rp) * RST + ch * 16;
      *(u32x4*)&Ut[byte0]       = lo;
      *(u32x4*)&Ut[byte0 + RST] = hi;
    }
  }
  {
    float4 v[2][4], vt[4];
    const bool tl = lane < 40;                 // tail units 320..359
    #pragma unroll
    for (int k = 0; k < 2; ++k) {
      const int u  = lane + (3 + k) * 64;
      const int ch = u / 36, rp = u - ch * 36;
      int cw = po + 2 * rp; if (cw >= WOUT_) cw -= WOUT_;
      #pragma unroll
      for (int m = 0; m < 4; ++m) {
        int qp = 4 * ch + m, c = (qp * 205) >> 10, s = qp - c * 5;
        v[k][m] = *(const float4*)&xb[(size_t)(c * HIN + rr[s]) * WIN + 2 * cw];
      }
    }
    if (tl) {
      const int u  = 320 + lane;
      const int ch = u / 36, rp = u - ch * 36;
      int cw = po + 2 * rp; if (cw >= WOUT_) cw -= WOUT_;
      #pragma unroll
      for (int m = 0; m < 4; ++m) {
        int qp = 4 * ch + m, c = (qp * 205) >> 10, s = qp - c * 5;
        vt[m] = *(const float4*)&xb[(size_t)(c * HIN + rr[s]) * WIN + 2 * cw];
      }
    }
    #pragma unroll
    for (int k = 0; k < 2; ++k) {
      const int u  = lane + (3 + k) * 64;
      const int ch = u / 36, rp = u - ch * 36;
      u32x4 lo, hi;
      #pragma unroll
      for (int m = 0; m < 4; ++m) { lo[m] = pack2(v[k][m].x, v[k][m].y);
                                    hi[m] = pack2(v[k][m].z, v[k][m].w); }
      const int byte0 = (2 * rp) * RST + ch * 16;
      *(u32x4*)&Ut[byte0]       = lo;
      *(u32x4*)&Ut[byte0 + RST] = hi;
    }
    if (tl) {
      const int u  = 320 + lane;
      const int ch = u / 36, rp = u - ch * 36;
      u32x4 lo, hi;
      #pragma unroll
      for (int m = 0; m < 4; ++m) { lo[m] = pack2(vt[m].x, vt[m].y);
                                    hi[m] = pack2(vt[m].z, vt[m].w); }
      const int byte0 = (2 * rp) * RST + ch * 16;
      *(u32x4*)&Ut[byte0]       = lo;
      *(u32x4*)&Ut[byte0 + RST] = hi;
    }
  }
  // no barrier: wave-private tile; compiler inserts the lgkmcnt RAW wait.

  // ---- MFMA: 8 j x 5 kb x 2 rows, depth-2 A-frag prefetch ----
  f32x16 acc0 = {};
  f32x16 acc1 = {};

  #pragma unroll
  for (int j = 0; j < 8; ++j) {
    bsh8 a2[5];
    if (j < 6) {
      #pragma unroll
      for (int kb = 0; kb < 5; ++kb)
        a2[kb] = *(const bsh8*)&cgx[(j + 2) * 2560 + kb * 512];
    }
    const int rb0 = (l31 + j) * RST;            // local rows 0..38
    const int rb1 = rb0 + 32 * RST;             // local rows 32..70
    #pragma unroll
    for (int kb = 0; kb < 5; ++kb) {
      const int cho = (2 * kb + half) * 16;
      bsh8 b0 = *(const bsh8*)&Ut[rb0 + cho];
      acc0 = __builtin_amdgcn_mfma_f32_32x32x16_bf16(a0[kb], b0, acc0, 0, 0, 0);
      bsh8 b1 = *(const bsh8*)&Ut[rb1 + cho];
      acc1 = __builtin_amdgcn_mfma_f32_32x32x16_bf16(a0[kb], b1, acc1, 0, 0, 0);
    }
    #pragma unroll
    for (int kb = 0; kb < 5; ++kb) { a0[kb] = a1[kb]; a1[kb] = a2[kb]; }
  }

  // ---- store: D col = l31 -> p, row o = (r&3) + 8*(r>>2) + 4*half ----
  const int p = po + l31;
  #pragma unroll
  for (int r = 0; r < 16; ++r) {
    int o = (r & 3) + 8 * (r >> 2) + 4 * half;
    size_t base = ((size_t)(b * COUT_ + o) * HOUT_ + xo) * WOUT_;
    if (p < WOUT_)
      __builtin_nontemporal_store(acc0[r], &out[base + p]);
    if (p + 32 < WOUT_)
      __builtin_nontemporal_store(acc1[r], &out[base + p + 32]);
  }
}

extern "C" void kernel_launch(void* const* d_in, const int* in_sizes, int n_in,
                              void* d_out, int out_size, void* d_ws, size_t ws_size,
                              hipStream_t stream) {
  const float* x        = (const float*)d_in[0];
  const int*   psi_idx  = (const int*)d_in[1];
  const float* psi_vals = (const float*)d_in[2];
  const float* weight   = (const float*)d_in[3];
  float* out = (float*)d_out;
  unsigned short* Cg = (unsigned short*)d_ws;   // 361*2560*8 bf16 = 14.8 MB

  coeff_kernel<<<dim3(HOUT_), 256, 0, stream>>>(psi_idx, psi_vals, weight, Cg);
  disco_main_kernel<<<dim3(12 * NB * HOUT_), 64, 0, stream>>>(x, Cg, out);
}